// Round 1
// baseline (1137.870 us; speedup 1.0000x reference)
//
#include <hip/hip_runtime.h>

#define N_NODES 100000
#define N_EDGES 1250000
#define D_FEAT 64

// One edge per 16 lanes; each lane handles 4 consecutive features (float4).
// Gather x[src] coalesced (16 lanes * 16B = 256B per edge), scatter-add into
// out[dst] with hardware fp32 atomics (unsafeAtomicAdd -> global_atomic_add_f32).
__global__ __launch_bounds__(256) void lgconv_scatter(
    const float* __restrict__ x,
    const int* __restrict__ src,
    const int* __restrict__ dst,
    float* __restrict__ out) {
    int tid  = blockIdx.x * blockDim.x + threadIdx.x;
    int edge = tid >> 4;              // 16 lanes per edge
    int f4   = (tid & 15) << 2;      // feature offset 0..60 step 4
    if (edge >= N_EDGES) return;

    int s = src[edge];
    int d = dst[edge];

    const float4 v = *reinterpret_cast<const float4*>(x + (size_t)s * D_FEAT + f4);
    float* o = out + (size_t)d * D_FEAT + f4;

    unsafeAtomicAdd(o + 0, v.x);
    unsafeAtomicAdd(o + 1, v.y);
    unsafeAtomicAdd(o + 2, v.z);
    unsafeAtomicAdd(o + 3, v.w);
}

extern "C" void kernel_launch(void* const* d_in, const int* in_sizes, int n_in,
                              void* d_out, int out_size, void* d_ws, size_t ws_size,
                              hipStream_t stream) {
    const float* x   = (const float*)d_in[1];
    const int*   ei  = (const int*)d_in[2];   // [2, N_EDGES] row-major
    const int*   src = ei;                     // edge_index[0]
    const int*   dst = ei + N_EDGES;           // edge_index[1]
    float*       out = (float*)d_out;

    // d_out is poisoned 0xAA before every timed launch — zero it first.
    hipMemsetAsync(out, 0, (size_t)out_size * sizeof(float), stream);

    const int total   = N_EDGES * 16;          // 16 lanes per edge
    const int block   = 256;
    const int grid    = (total + block - 1) / block;
    lgconv_scatter<<<grid, block, 0, stream>>>(x, src, dst, out);
}

// Round 2
// 272.145 us; speedup vs baseline: 4.1811x; 4.1811x over previous
//
#include <hip/hip_runtime.h>

#define N_NODES 100000
#define N_EDGES 1250000
#define D_FEAT 64
#define SCAN_BLOCK 1024
#define N_SCAN_BLOCKS ((N_NODES + SCAN_BLOCK - 1) / SCAN_BLOCK)   // 98

// ---------------- fallback (round-1): edge-parallel fp32 atomics ------------
__global__ __launch_bounds__(256) void lgconv_scatter(
    const float* __restrict__ x, const int* __restrict__ src,
    const int* __restrict__ dst, float* __restrict__ out) {
    int tid  = blockIdx.x * blockDim.x + threadIdx.x;
    int edge = tid >> 4;
    int f4   = (tid & 15) << 2;
    if (edge >= N_EDGES) return;
    int s = src[edge], d = dst[edge];
    const float4 v = *reinterpret_cast<const float4*>(x + (size_t)s * D_FEAT + f4);
    float* o = out + (size_t)d * D_FEAT + f4;
    unsafeAtomicAdd(o + 0, v.x); unsafeAtomicAdd(o + 1, v.y);
    unsafeAtomicAdd(o + 2, v.z); unsafeAtomicAdd(o + 3, v.w);
}

// ---------------- CSR-binning path ------------------------------------------
// ws layout (int32):
//   offsets        [0, N_NODES+1)        counts -> exclusive scan -> row starts
//   cursor         [N_NODES+1, 2N+1)     running fill cursor per node
//   bins           [2N+1, 2N+1+E)        src node id per binned edge
//   blockSums      [next, +N_SCAN_BLOCKS)
//   blockSumsScan  [next, +N_SCAN_BLOCKS)

__global__ __launch_bounds__(256) void hist_kernel(
    const int* __restrict__ dst, int* __restrict__ counts) {
    int e = blockIdx.x * blockDim.x + threadIdx.x;
    if (e < N_EDGES) atomicAdd(&counts[dst[e]], 1);
}

__global__ __launch_bounds__(SCAN_BLOCK) void scan_blocks_kernel(
    int* __restrict__ counts, int* __restrict__ blockSums) {
    __shared__ int tmp[SCAN_BLOCK];
    int i = blockIdx.x * SCAN_BLOCK + threadIdx.x;
    int v = (i < N_NODES) ? counts[i] : 0;
    tmp[threadIdx.x] = v;
    __syncthreads();
    for (int off = 1; off < SCAN_BLOCK; off <<= 1) {
        int t = (threadIdx.x >= off) ? tmp[threadIdx.x - off] : 0;
        __syncthreads();
        tmp[threadIdx.x] += t;
        __syncthreads();
    }
    int inc = tmp[threadIdx.x];
    if (i < N_NODES) counts[i] = inc - v;          // exclusive within block
    if (threadIdx.x == SCAN_BLOCK - 1) blockSums[blockIdx.x] = inc;
}

__global__ __launch_bounds__(128) void scan_sums_kernel(
    const int* __restrict__ blockSums, int* __restrict__ blockSumsScan) {
    __shared__ int tmp[128];
    int t = threadIdx.x;
    int v = (t < N_SCAN_BLOCKS) ? blockSums[t] : 0;
    tmp[t] = v;
    __syncthreads();
    for (int off = 1; off < 128; off <<= 1) {
        int u = (t >= off) ? tmp[t - off] : 0;
        __syncthreads();
        tmp[t] += u;
        __syncthreads();
    }
    if (t < N_SCAN_BLOCKS) blockSumsScan[t] = tmp[t] - v;  // exclusive
}

__global__ __launch_bounds__(256) void scan_fixup_kernel(
    int* __restrict__ offsets, int* __restrict__ cursor,
    const int* __restrict__ blockSumsScan) {
    int i = blockIdx.x * blockDim.x + threadIdx.x;
    if (i < N_NODES) {
        int off = offsets[i] + blockSumsScan[i / SCAN_BLOCK];
        offsets[i] = off;
        cursor[i]  = off;
    }
    if (i == 0) offsets[N_NODES] = N_EDGES;
}

__global__ __launch_bounds__(256) void fill_kernel(
    const int* __restrict__ src, const int* __restrict__ dst,
    int* __restrict__ cursor, int* __restrict__ bins) {
    int e = blockIdx.x * blockDim.x + threadIdx.x;
    if (e >= N_EDGES) return;
    int d = dst[e];
    int p = atomicAdd(&cursor[d], 1);
    bins[p] = src[e];
}

// 16 lanes per node; lane handles 4 consecutive features (float4).
__global__ __launch_bounds__(256) void gather_sum_kernel(
    const float* __restrict__ x, const int* __restrict__ offsets,
    const int* __restrict__ bins, float* __restrict__ out) {
    int tid  = blockIdx.x * blockDim.x + threadIdx.x;
    int node = tid >> 4;
    int f4   = (tid & 15) << 2;
    if (node >= N_NODES) return;
    int beg = offsets[node];
    int end = offsets[node + 1];
    float4 acc = make_float4(0.f, 0.f, 0.f, 0.f);
    int k = beg;
    for (; k + 1 < end; k += 2) {
        int s0 = bins[k], s1 = bins[k + 1];
        const float4 a = *reinterpret_cast<const float4*>(x + (size_t)s0 * D_FEAT + f4);
        const float4 b = *reinterpret_cast<const float4*>(x + (size_t)s1 * D_FEAT + f4);
        acc.x += a.x; acc.y += a.y; acc.z += a.z; acc.w += a.w;
        acc.x += b.x; acc.y += b.y; acc.z += b.z; acc.w += b.w;
    }
    if (k < end) {
        int s0 = bins[k];
        const float4 a = *reinterpret_cast<const float4*>(x + (size_t)s0 * D_FEAT + f4);
        acc.x += a.x; acc.y += a.y; acc.z += a.z; acc.w += a.w;
    }
    *reinterpret_cast<float4*>(out + (size_t)node * D_FEAT + f4) = acc;
}

extern "C" void kernel_launch(void* const* d_in, const int* in_sizes, int n_in,
                              void* d_out, int out_size, void* d_ws, size_t ws_size,
                              hipStream_t stream) {
    const float* x   = (const float*)d_in[1];
    const int*   ei  = (const int*)d_in[2];
    const int*   src = ei;
    const int*   dst = ei + N_EDGES;
    float*       out = (float*)d_out;

    const size_t needed = (size_t)(2 * N_NODES + 1 + N_EDGES + 2 * N_SCAN_BLOCKS) * sizeof(int);
    if (ws_size < needed) {
        // fallback: atomic scatter (round-1 path)
        hipMemsetAsync(out, 0, (size_t)out_size * sizeof(float), stream);
        const int total = N_EDGES * 16;
        lgconv_scatter<<<(total + 255) / 256, 256, 0, stream>>>(x, src, dst, out);
        return;
    }

    int* offsets       = (int*)d_ws;
    int* cursor        = offsets + (N_NODES + 1);
    int* bins          = cursor + N_NODES;
    int* blockSums     = bins + N_EDGES;
    int* blockSumsScan = blockSums + N_SCAN_BLOCKS;

    // 1) zero counts, histogram of dst
    hipMemsetAsync(offsets, 0, (size_t)(N_NODES + 1) * sizeof(int), stream);
    hist_kernel<<<(N_EDGES + 255) / 256, 256, 0, stream>>>(dst, offsets);

    // 2) exclusive scan -> offsets, cursor
    scan_blocks_kernel<<<N_SCAN_BLOCKS, SCAN_BLOCK, 0, stream>>>(offsets, blockSums);
    scan_sums_kernel<<<1, 128, 0, stream>>>(blockSums, blockSumsScan);
    scan_fixup_kernel<<<(N_NODES + 255) / 256, 256, 0, stream>>>(offsets, cursor, blockSumsScan);

    // 3) bin edges by dst
    fill_kernel<<<(N_EDGES + 255) / 256, 256, 0, stream>>>(src, dst, cursor, bins);

    // 4) atomic-free gather-sum (writes every out row -> no out memset needed)
    const int total = N_NODES * 16;
    gather_sum_kernel<<<(total + 255) / 256, 256, 0, stream>>>(x, offsets, bins, out);
}

// Round 3
// 166.636 us; speedup vs baseline: 6.8285x; 1.6332x over previous
//
#include <hip/hip_runtime.h>

#define N_NODES 100000
#define N_EDGES 1250000
#define D_FEAT 64

#define NB_SHIFT 7
#define NODES_PER_B 128                                   // 1 << NB_SHIFT
#define N_BUCKETS ((N_NODES + NODES_PER_B - 1) / NODES_PER_B)  // 782
#define NB_PAD 1024                                       // padded for scans
#define CHUNK 4096
#define N_CHUNKS ((N_EDGES + CHUNK - 1) / CHUNK)          // 306
#define MAX_BUCKET_EDGES 2048                             // mean 1598, ~11 sigma headroom
#define SRC_BITS 17                                       // 100000 < 2^17
#define SRC_MASK ((1u << SRC_BITS) - 1u)

// ---------------- fallback: edge-parallel fp32 atomics ----------------------
__global__ __launch_bounds__(256) void lgconv_scatter(
    const float* __restrict__ x, const int* __restrict__ src,
    const int* __restrict__ dst, float* __restrict__ out) {
    int tid  = blockIdx.x * blockDim.x + threadIdx.x;
    int edge = tid >> 4;
    int f4   = (tid & 15) << 2;
    if (edge >= N_EDGES) return;
    int s = src[edge], d = dst[edge];
    const float4 v = *reinterpret_cast<const float4*>(x + (size_t)s * D_FEAT + f4);
    float* o = out + (size_t)d * D_FEAT + f4;
    unsafeAtomicAdd(o + 0, v.x); unsafeAtomicAdd(o + 1, v.y);
    unsafeAtomicAdd(o + 2, v.z); unsafeAtomicAdd(o + 3, v.w);
}

// ---------------- P1: coarse bucket histogram (LDS-staged) ------------------
__global__ __launch_bounds__(256) void p1_hist(
    const int* __restrict__ dst, int* __restrict__ counts) {
    __shared__ int h[NB_PAD];
    for (int i = threadIdx.x; i < NB_PAD; i += 256) h[i] = 0;
    __syncthreads();
    int base = blockIdx.x * CHUNK;
    int end  = min(base + CHUNK, N_EDGES);
    for (int e = base + (int)threadIdx.x; e < end; e += 256)
        atomicAdd(&h[dst[e] >> NB_SHIFT], 1);
    __syncthreads();
    for (int b = threadIdx.x; b < N_BUCKETS; b += 256)
        if (h[b]) atomicAdd(&counts[b], h[b]);
}

// ---------------- S: exclusive scan of 782 bucket counts --------------------
__global__ __launch_bounds__(1024) void s_scan(
    const int* __restrict__ counts, int* __restrict__ bucketBase,
    int* __restrict__ gCursor) {
    __shared__ int tmp[1024];
    int t = threadIdx.x;
    int v = (t < N_BUCKETS) ? counts[t] : 0;
    tmp[t] = v;
    __syncthreads();
    for (int off = 1; off < 1024; off <<= 1) {
        int u = (t >= off) ? tmp[t - off] : 0;
        __syncthreads();
        tmp[t] += u;
        __syncthreads();
    }
    int excl = tmp[t] - v;
    if (t < N_BUCKETS) { bucketBase[t] = excl; gCursor[t] = excl; }
    if (t == N_BUCKETS - 1) bucketBase[N_BUCKETS] = tmp[t];   // == N_EDGES
}

// ---------------- P2: LDS counting-sort scatter into bucket runs ------------
__global__ __launch_bounds__(256) void p2_scatter(
    const int* __restrict__ src, const int* __restrict__ dst,
    int* __restrict__ gCursor, unsigned int* __restrict__ bins) {
    __shared__ int hist[NB_PAD];        // counts, later reused as runBase
    __shared__ int scanBase[NB_PAD];    // local exclusive scan
    __shared__ int cur[NB_PAD];         // local fill cursor
    __shared__ int scanTmp[256];
    __shared__ unsigned int   stageV[CHUNK];
    __shared__ unsigned short stageB[CHUNK];
    int t = threadIdx.x;
    for (int i = t; i < NB_PAD; i += 256) { hist[i] = 0; cur[i] = 0; }
    __syncthreads();
    int base = blockIdx.x * CHUNK;
    int cnt  = min(CHUNK, N_EDGES - base);
    for (int i = t; i < cnt; i += 256)
        atomicAdd(&hist[dst[base + i] >> NB_SHIFT], 1);
    __syncthreads();
    // exclusive scan of hist[0..1023] with 4 elements/thread
    int b0 = 4 * t;
    int a0 = hist[b0], a1 = hist[b0 + 1], a2 = hist[b0 + 2], a3 = hist[b0 + 3];
    int tsum = a0 + a1 + a2 + a3;
    scanTmp[t] = tsum;
    __syncthreads();
    for (int off = 1; off < 256; off <<= 1) {
        int u = (t >= off) ? scanTmp[t - off] : 0;
        __syncthreads();
        scanTmp[t] += u;
        __syncthreads();
    }
    int excl = scanTmp[t] - tsum;
    scanBase[b0]     = excl;
    scanBase[b0 + 1] = excl + a0;
    scanBase[b0 + 2] = excl + a0 + a1;
    scanBase[b0 + 3] = excl + a0 + a1 + a2;
    __syncthreads();
    // reserve global runs; overwrite hist with runBase
    for (int b = t; b < N_BUCKETS; b += 256) {
        int c = hist[b];
        hist[b] = c ? atomicAdd(&gCursor[b], c) : 0;
    }
    // place edges into stage, grouped by bucket
    __syncthreads();
    for (int i = t; i < cnt; i += 256) {
        int d = dst[base + i];
        int s = src[base + i];
        int b = d >> NB_SHIFT;
        unsigned int packed = ((unsigned int)(d & (NODES_PER_B - 1)) << SRC_BITS)
                            | (unsigned int)s;
        int pos = scanBase[b] + atomicAdd(&cur[b], 1);
        stageV[pos] = packed;
        stageB[pos] = (unsigned short)b;
    }
    __syncthreads();
    // write out: consecutive threads -> consecutive addresses within runs
    for (int i = t; i < cnt; i += 256) {
        int b = stageB[i];
        int gpos = hist[b] + (i - scanBase[b]);
        bins[gpos] = stageV[i];
    }
}

// ---------------- A: per-bucket LDS CSR + atomic-free gather-sum ------------
__global__ __launch_bounds__(256) void a_accum(
    const float* __restrict__ x, const int* __restrict__ bucketBase,
    const unsigned int* __restrict__ bins, float* __restrict__ out) {
    __shared__ int nodeOff[NODES_PER_B + 1];
    __shared__ int cur[NODES_PER_B];
    __shared__ int cntArr[NODES_PER_B];
    __shared__ int scanTmp2[NODES_PER_B];
    __shared__ unsigned int srcs[MAX_BUCKET_EDGES];
    int t = threadIdx.x;
    int b = blockIdx.x;
    int base = bucketBase[b];
    int cnt  = bucketBase[b + 1] - base;
    if (cnt > MAX_BUCKET_EDGES) cnt = MAX_BUCKET_EDGES;   // statistically impossible
    if (t < NODES_PER_B) cntArr[t] = 0;
    __syncthreads();
    for (int i = t; i < cnt; i += 256)
        atomicAdd(&cntArr[bins[base + i] >> SRC_BITS], 1);
    __syncthreads();
    // exclusive scan over 128 node counts (threads 0..127, all hit barriers)
    int v = (t < NODES_PER_B) ? cntArr[t] : 0;
    if (t < NODES_PER_B) scanTmp2[t] = v;
    __syncthreads();
    for (int off = 1; off < NODES_PER_B; off <<= 1) {
        int u = (t < NODES_PER_B && t >= off) ? scanTmp2[t - off] : 0;
        __syncthreads();
        if (t < NODES_PER_B) scanTmp2[t] += u;
        __syncthreads();
    }
    if (t < NODES_PER_B) {
        int excl = scanTmp2[t] - v;
        nodeOff[t] = excl;
        cur[t]     = excl;
    }
    if (t == 0) nodeOff[NODES_PER_B] = cnt;
    __syncthreads();
    for (int i = t; i < cnt; i += 256) {
        unsigned int p = bins[base + i];
        int local = (int)(p >> SRC_BITS);
        int pos = atomicAdd(&cur[local], 1);
        srcs[pos] = p & SRC_MASK;
    }
    __syncthreads();
    // 16 lanes per node, float4 per lane; unroll-2 for memory parallelism
    int lane4 = (t & 15) << 2;
    for (int g = 0; g < NODES_PER_B / 16; ++g) {
        int local = g * 16 + (t >> 4);
        int node  = b * NODES_PER_B + local;
        int beg = nodeOff[local], end = nodeOff[local + 1];
        float4 acc = make_float4(0.f, 0.f, 0.f, 0.f);
        int k = beg;
        for (; k + 1 < end; k += 2) {
            unsigned int s0 = srcs[k], s1 = srcs[k + 1];
            const float4 u = *reinterpret_cast<const float4*>(x + (size_t)s0 * D_FEAT + lane4);
            const float4 w = *reinterpret_cast<const float4*>(x + (size_t)s1 * D_FEAT + lane4);
            acc.x += u.x + w.x; acc.y += u.y + w.y;
            acc.z += u.z + w.z; acc.w += u.w + w.w;
        }
        if (k < end) {
            unsigned int s0 = srcs[k];
            const float4 u = *reinterpret_cast<const float4*>(x + (size_t)s0 * D_FEAT + lane4);
            acc.x += u.x; acc.y += u.y; acc.z += u.z; acc.w += u.w;
        }
        if (node < N_NODES)
            *reinterpret_cast<float4*>(out + (size_t)node * D_FEAT + lane4) = acc;
    }
}

extern "C" void kernel_launch(void* const* d_in, const int* in_sizes, int n_in,
                              void* d_out, int out_size, void* d_ws, size_t ws_size,
                              hipStream_t stream) {
    const float* x   = (const float*)d_in[1];
    const int*   ei  = (const int*)d_in[2];
    const int*   src = ei;
    const int*   dst = ei + N_EDGES;
    float*       out = (float*)d_out;

    // ws layout (int32): counts[782] | bucketBase[783] | gCursor[782] | bins[E]
    const size_t needed = (size_t)(N_BUCKETS + (N_BUCKETS + 1) + N_BUCKETS + N_EDGES) * sizeof(int);
    if (ws_size < needed) {
        hipMemsetAsync(out, 0, (size_t)out_size * sizeof(float), stream);
        const int total = N_EDGES * 16;
        lgconv_scatter<<<(total + 255) / 256, 256, 0, stream>>>(x, src, dst, out);
        return;
    }

    int*          counts     = (int*)d_ws;
    int*          bucketBase = counts + N_BUCKETS;
    int*          gCursor    = bucketBase + (N_BUCKETS + 1);
    unsigned int* bins       = (unsigned int*)(gCursor + N_BUCKETS);

    hipMemsetAsync(counts, 0, (size_t)N_BUCKETS * sizeof(int), stream);
    p1_hist<<<N_CHUNKS, 256, 0, stream>>>(dst, counts);
    s_scan<<<1, 1024, 0, stream>>>(counts, bucketBase, gCursor);
    p2_scatter<<<N_CHUNKS, 256, 0, stream>>>(src, dst, gCursor, bins);
    a_accum<<<N_BUCKETS, 256, 0, stream>>>(x, bucketBase, bins, out);
}

// Round 4
// 143.207 us; speedup vs baseline: 7.9456x; 1.1636x over previous
//
#include <hip/hip_runtime.h>

#define N_NODES 100000
#define N_EDGES 1250000
#define D_FEAT 64

#define NB_SHIFT 7
#define NODES_PER_B 128
#define N_BUCKETS ((N_NODES + NODES_PER_B - 1) / NODES_PER_B)   // 782
#define TROW (N_BUCKETS + 1)                                     // 783
#define NB_PAD 1024
#define MAX_BUCKET_EDGES 2048        // mean 1600, sigma 40 -> 11 sigma headroom
#define SRC_BITS 17
#define SRC_MASK ((1u << SRC_BITS) - 1u)

// ---------------- fallback: edge-parallel fp32 atomics ----------------------
__global__ __launch_bounds__(256) void lgconv_scatter(
    const float* __restrict__ x, const int* __restrict__ src,
    const int* __restrict__ dst, float* __restrict__ out) {
    int tid  = blockIdx.x * blockDim.x + threadIdx.x;
    int edge = tid >> 4;
    int f4   = (tid & 15) << 2;
    if (edge >= N_EDGES) return;
    int s = src[edge], d = dst[edge];
    const float4 v = *reinterpret_cast<const float4*>(x + (size_t)s * D_FEAT + f4);
    float* o = out + (size_t)d * D_FEAT + f4;
    unsafeAtomicAdd(o + 0, v.x); unsafeAtomicAdd(o + 1, v.y);
    unsafeAtomicAdd(o + 2, v.z); unsafeAtomicAdd(o + 3, v.w);
}

// ---------------- k1: per-chunk LDS counting sort by bucket -----------------
// Writes: bins[base..base+cnt) = chunk edges sorted by bucket (packed
// localdst<<17|src), table[c*783 + 0..782] = exclusive bucket offsets
// (entry 782 == cnt). All global writes coalesced; no global atomics.
template <int CHUNK, int BLOCK>
__global__ __launch_bounds__(BLOCK) void k1_sort(
    const int* __restrict__ src, const int* __restrict__ dst,
    unsigned int* __restrict__ bins, int* __restrict__ table) {
    __shared__ int hist[NB_PAD];
    __shared__ int scanBase[NB_PAD];
    __shared__ int cur[NB_PAD];
    __shared__ int scanTmp[BLOCK];
    __shared__ unsigned int stage[CHUNK];
    const int t    = threadIdx.x;
    const int c    = blockIdx.x;
    const int base = c * CHUNK;
    const int cnt  = min(CHUNK, N_EDGES - base);
    for (int i = t; i < NB_PAD; i += BLOCK) { hist[i] = 0; cur[i] = 0; }
    __syncthreads();
    for (int i = t; i < cnt; i += BLOCK)
        atomicAdd(&hist[dst[base + i] >> NB_SHIFT], 1);
    __syncthreads();
    // exclusive scan of hist[0..NB_PAD)
    constexpr int P = NB_PAD / BLOCK;
    int loc[P]; int tsum = 0;
    #pragma unroll
    for (int q = 0; q < P; ++q) { loc[q] = hist[t * P + q]; tsum += loc[q]; }
    scanTmp[t] = tsum;
    __syncthreads();
    for (int off = 1; off < BLOCK; off <<= 1) {
        int u = (t >= off) ? scanTmp[t - off] : 0;
        __syncthreads();
        scanTmp[t] += u;
        __syncthreads();
    }
    int run = scanTmp[t] - tsum;
    #pragma unroll
    for (int q = 0; q < P; ++q) { scanBase[t * P + q] = run; run += loc[q]; }
    __syncthreads();
    // dump offset row (scanBase[782] == cnt since hist[b>=782]==0)
    for (int i = t; i < TROW; i += BLOCK) table[c * TROW + i] = scanBase[i];
    // place edges into LDS stage grouped by bucket
    for (int i = t; i < cnt; i += BLOCK) {
        int d = dst[base + i], s = src[base + i];
        int b = d >> NB_SHIFT;
        unsigned int packed = ((unsigned int)(d & (NODES_PER_B - 1)) << SRC_BITS)
                            | (unsigned int)s;
        int pos = scanBase[b] + atomicAdd(&cur[b], 1);
        stage[pos] = packed;
    }
    __syncthreads();
    // coalesced dump of sorted chunk
    for (int i = t; i < cnt; i += BLOCK) bins[base + i] = stage[i];
}

// ---------------- k2: assemble bucket from fragments, CSR, gather-sum -------
template <int CHUNK, int NCH>
__global__ __launch_bounds__(256) void k2_accum(
    const float* __restrict__ x, const unsigned int* __restrict__ bins,
    const int* __restrict__ table, float* __restrict__ out) {
    constexpr int CPT = (NCH + 255) / 256;    // chunks per thread (phase A)
    constexpr int LPC = CHUNK / 256;          // lanes per fragment (phase B)
    constexpr int CPI = 256 / LPC;            // fragments per iteration
    __shared__ int            startA[CPT * 256];
    __shared__ unsigned short lenA[CPT * 256];
    __shared__ int            destB[CPT * 256];
    __shared__ int            scanTmp[256];
    __shared__ unsigned int   raw[MAX_BUCKET_EDGES];
    __shared__ unsigned int   srcs[MAX_BUCKET_EDGES];
    __shared__ int cntArr[NODES_PER_B];
    __shared__ int nodeOff[NODES_PER_B + 1];
    __shared__ int curN[NODES_PER_B];
    __shared__ int s2[NODES_PER_B];
    const int t = threadIdx.x;
    const int b = blockIdx.x;

    // phase A: fragment start/len per chunk + exclusive scan -> LDS dest base
    int myLen[CPT]; int lsum = 0;
    #pragma unroll
    for (int q = 0; q < CPT; ++q) {
        int c = t * CPT + q;
        int st = 0, len = 0;
        if (c < NCH) {
            st  = table[c * TROW + b];
            len = table[c * TROW + b + 1] - st;
        }
        startA[t * CPT + q] = st;
        lenA[t * CPT + q]   = (unsigned short)len;
        myLen[q] = len; lsum += len;
    }
    scanTmp[t] = lsum;
    __syncthreads();
    for (int off = 1; off < 256; off <<= 1) {
        int u = (t >= off) ? scanTmp[t - off] : 0;
        __syncthreads();
        scanTmp[t] += u;
        __syncthreads();
    }
    int run = scanTmp[t] - lsum;
    #pragma unroll
    for (int q = 0; q < CPT; ++q) { destB[t * CPT + q] = run; run += myLen[q]; }
    int cntTot = scanTmp[255];
    if (cntTot > MAX_BUCKET_EDGES) cntTot = MAX_BUCKET_EDGES;  // never in practice
    __syncthreads();

    // phase B: gather fragments into raw[] (LPC lanes per fragment)
    const int cj = t / LPC;
    const int jj = t % LPC;
    for (int c0 = 0; c0 < NCH; c0 += CPI) {
        int c = c0 + cj;
        if (c < NCH) {
            int len = lenA[c], st = startA[c], db = destB[c];
            const unsigned int* p = bins + (size_t)c * CHUNK + st;
            if (jj < len) raw[db + jj] = p[jj];
            if (jj == LPC - 1)
                for (int q = LPC; q < len; ++q) raw[db + q] = p[q];  // rare tail
        }
    }
    __syncthreads();

    // phase C: 128-node CSR in LDS
    if (t < NODES_PER_B) cntArr[t] = 0;
    __syncthreads();
    for (int i = t; i < cntTot; i += 256)
        atomicAdd(&cntArr[raw[i] >> SRC_BITS], 1);
    __syncthreads();
    int v = (t < NODES_PER_B) ? cntArr[t] : 0;
    if (t < NODES_PER_B) s2[t] = v;
    __syncthreads();
    for (int off = 1; off < NODES_PER_B; off <<= 1) {
        int u = (t < NODES_PER_B && t >= off) ? s2[t - off] : 0;
        __syncthreads();
        if (t < NODES_PER_B) s2[t] += u;
        __syncthreads();
    }
    if (t < NODES_PER_B) { nodeOff[t] = s2[t] - v; curN[t] = s2[t] - v; }
    if (t == 0) nodeOff[NODES_PER_B] = cntTot;
    __syncthreads();
    for (int i = t; i < cntTot; i += 256) {
        unsigned int p = raw[i];
        int pos = atomicAdd(&curN[p >> SRC_BITS], 1);
        srcs[pos] = p & SRC_MASK;
    }
    __syncthreads();

    // phase D: 16 lanes/node float4 gather-sum, unroll-4 for MLP
    int lane4 = (t & 15) << 2;
    for (int g = 0; g < NODES_PER_B / 16; ++g) {
        int local = g * 16 + (t >> 4);
        int node  = b * NODES_PER_B + local;
        int beg = nodeOff[local], end = nodeOff[local + 1];
        float4 acc = make_float4(0.f, 0.f, 0.f, 0.f);
        int k = beg;
        for (; k + 3 < end; k += 4) {
            unsigned int i0 = srcs[k], i1 = srcs[k+1], i2 = srcs[k+2], i3 = srcs[k+3];
            const float4 a = *reinterpret_cast<const float4*>(x + (size_t)i0 * D_FEAT + lane4);
            const float4 c = *reinterpret_cast<const float4*>(x + (size_t)i1 * D_FEAT + lane4);
            const float4 d = *reinterpret_cast<const float4*>(x + (size_t)i2 * D_FEAT + lane4);
            const float4 e = *reinterpret_cast<const float4*>(x + (size_t)i3 * D_FEAT + lane4);
            acc.x += a.x + c.x + d.x + e.x;
            acc.y += a.y + c.y + d.y + e.y;
            acc.z += a.z + c.z + d.z + e.z;
            acc.w += a.w + c.w + d.w + e.w;
        }
        for (; k < end; ++k) {
            unsigned int i0 = srcs[k];
            const float4 a = *reinterpret_cast<const float4*>(x + (size_t)i0 * D_FEAT + lane4);
            acc.x += a.x; acc.y += a.y; acc.z += a.z; acc.w += a.w;
        }
        if (node < N_NODES)
            *reinterpret_cast<float4*>(out + (size_t)node * D_FEAT + lane4) = acc;
    }
}

extern "C" void kernel_launch(void* const* d_in, const int* in_sizes, int n_in,
                              void* d_out, int out_size, void* d_ws, size_t ws_size,
                              hipStream_t stream) {
    const float* x   = (const float*)d_in[1];
    const int*   ei  = (const int*)d_in[2];
    const int*   src = ei;
    const int*   dst = ei + N_EDGES;
    float*       out = (float*)d_out;

    constexpr int CH1  = 2048;
    constexpr int NCH1 = (N_EDGES + CH1 - 1) / CH1;   // 611
    constexpr int CH2  = 4096;
    constexpr int NCH2 = (N_EDGES + CH2 - 1) / CH2;   // 306
    const size_t need1 = ((size_t)N_EDGES + (size_t)NCH1 * TROW) * sizeof(int); // ~6.9 MB
    const size_t need2 = ((size_t)N_EDGES + (size_t)NCH2 * TROW) * sizeof(int); // ~6.0 MB

    if (ws_size >= need1) {
        unsigned int* bins  = (unsigned int*)d_ws;
        int*          table = (int*)(bins + N_EDGES);
        k1_sort<CH1, 256><<<NCH1, 256, 0, stream>>>(src, dst, bins, table);
        k2_accum<CH1, NCH1><<<N_BUCKETS, 256, 0, stream>>>(x, bins, table, out);
    } else if (ws_size >= need2) {
        unsigned int* bins  = (unsigned int*)d_ws;
        int*          table = (int*)(bins + N_EDGES);
        k1_sort<CH2, 512><<<NCH2, 512, 0, stream>>>(src, dst, bins, table);
        k2_accum<CH2, NCH2><<<N_BUCKETS, 256, 0, stream>>>(x, bins, table, out);
    } else {
        hipMemsetAsync(out, 0, (size_t)out_size * sizeof(float), stream);
        const int total = N_EDGES * 16;
        lgconv_scatter<<<(total + 255) / 256, 256, 0, stream>>>(x, src, dst, out);
    }
}